// Round 4
// baseline (74.623 us; speedup 1.0000x reference)
//
#include <hip/hip_runtime.h>
#include <math.h>

// Problem constants (fixed by setup_inputs: N=1024, H=W=256, B=64).
#define HCONST 256
#define WCONST 256
#define ROWS   64                 // rows per block (stripe)
#define TILES  (HCONST / ROWS)    // 4 stripes per batch image
#define CHUNK  64                 // gaussians per LDS refill

// ---------------------------------------------------------------------------
// Single fused kernel, LDS-broadcast formulation, 64-row stripes.
//
// Math: g = fx(x)*fy(y) separable & positive -> grid max = max(fx)*max(fy),
// attained at the grid point nearest mu (step 1/255); the 1/(2*pi*sx*sy)
// prefactor cancels in g/max(g). With ax=1/(2 sx^2), cx=ax*dxmin^2:
//   g_norm[n,y,x] = pred[n] * exp(cx - ax*dx^2) * exp(cy - ay*dy^2)
// and segment-sum = per-batch sum of rank-1 outer products.
//
// Block = (batch, 64-row stripe), 256 threads, grid = 64*4 = 256 blocks.
// Thread owns 4 adjacent columns (x = 4*xi..4*xi+3, xi = t&63) x 16 rows
// (quarter q = t>>6 -> rows y0+16q..y0+16q+15) = 64 fp32 accumulators.
// Per gaussian per thread: 1 b128 prm read + 4 b128 fy reads (all uniform
// broadcasts) + 4 fx exps + 64 FMAs  ->  LDS-instr/FMA = 5/64 (was 5/32).
// Stores: global_store_dwordx4; one wave covers a full 1 KB row per instr.
// Output written exactly once -> no pre-zero needed.
// ---------------------------------------------------------------------------
__global__ __launch_bounds__(256) void fused_kernel(
    const float* __restrict__ pred,
    const float* __restrict__ nodes,      // (N,4): mux, muy, sx, sy
    const int*   __restrict__ batch_list,
    int N,
    float* __restrict__ out)
{
    const int b  = blockIdx.x / TILES;
    const int ty = blockIdx.x % TILES;
    const int y0 = ty * ROWS;
    const int t  = threadIdx.x;
    const int xi = t & 63;          // column group: x = 4*xi .. 4*xi+3
    const int q  = t >> 6;          // row quarter: rows y0+16q .. y0+16q+15

    __shared__ int    s_idx[1024];
    __shared__ int    s_cnt;
    __shared__ float4 s_prm[CHUNK];          // {mux, ax, cx, 0}
    __shared__ float  s_fy[CHUNK][ROWS];     // pred * fy for stripe rows

    if (t == 0) s_cnt = 0;
    __syncthreads();
    for (int n = t; n < N; n += 256) {
        if (batch_list[n] == b) {
            int p = atomicAdd(&s_cnt, 1);
            s_idx[p] = n;
        }
    }
    __syncthreads();
    const int cnt = s_cnt;

    const float step = 1.0f / 255.0f;
    const float xs0 = (4 * xi)     * step;
    const float xs1 = (4 * xi + 1) * step;
    const float xs2 = (4 * xi + 2) * step;
    const float xs3 = (4 * xi + 3) * step;

    float4 acc[16];
#pragma unroll
    for (int r = 0; r < 16; ++r) acc[r] = make_float4(0.f, 0.f, 0.f, 0.f);

    for (int c0 = 0; c0 < cnt; c0 += CHUNK) {
        const int cc = min(CHUNK, cnt - c0);

        // --- per-gaussian x-params ---
        for (int p = t; p < cc; p += 256) {
            const int n = s_idx[c0 + p];
            const float4 nd = ((const float4*)nodes)[n];
            const float ax = 1.0f / (2.0f * nd.z * nd.z);
            float ni = roundf(nd.x * 255.0f);
            ni = fminf(fmaxf(ni, 0.0f), 255.0f);
            const float dxm = ni * step - nd.x;
            s_prm[p] = make_float4(nd.x, ax, ax * dxm * dxm, 0.0f);
        }
        // --- per-gaussian fy for the stripe's 64 rows (pred folded in) ---
        for (int it = t; it < cc * ROWS; it += 256) {
            const int g  = it >> 6;
            const int yy = it & 63;
            const int n  = s_idx[c0 + g];
            const float4 nd = ((const float4*)nodes)[n];
            const float ay = 1.0f / (2.0f * nd.w * nd.w);
            float ni = roundf(nd.y * 255.0f);
            ni = fminf(fmaxf(ni, 0.0f), 255.0f);
            const float dym = ni * step - nd.y;
            const float dy  = (y0 + yy) * step - nd.y;
            s_fy[g][yy] = pred[n] * __expf(ay * (dym * dym - dy * dy));
        }
        __syncthreads();

        // --- accumulate ---
        for (int g = 0; g < cc; ++g) {
            const float4 prm = s_prm[g];                  // uniform broadcast
            const float dx0 = xs0 - prm.x;
            const float dx1 = xs1 - prm.x;
            const float dx2 = xs2 - prm.x;
            const float dx3 = xs3 - prm.x;
            const float e0 = __expf(prm.z - prm.y * dx0 * dx0);
            const float e1 = __expf(prm.z - prm.y * dx1 * dx1);
            const float e2 = __expf(prm.z - prm.y * dx2 * dx2);
            const float e3 = __expf(prm.z - prm.y * dx3 * dx3);
            const float4* fy4 = (const float4*)&s_fy[g][q * 16];
#pragma unroll
            for (int k = 0; k < 4; ++k) {
                const float4 f = fy4[k];                  // uniform b128
#pragma unroll
                for (int j = 0; j < 4; ++j) {
                    const float fv = (j == 0) ? f.x : (j == 1) ? f.y
                                   : (j == 2) ? f.z : f.w;
                    float4& a = acc[k * 4 + j];
                    a.x = fmaf(fv, e0, a.x);
                    a.y = fmaf(fv, e1, a.y);
                    a.z = fmaf(fv, e2, a.z);
                    a.w = fmaf(fv, e3, a.w);
                }
            }
        }
        __syncthreads();   // before next chunk overwrites s_prm/s_fy
    }

    // --- store: float4 per row; a wave covers a full 1 KB row per instr ---
    float* o = out + ((size_t)b * HCONST + y0 + q * 16) * WCONST + 4 * xi;
#pragma unroll
    for (int r = 0; r < 16; ++r)
        ((float4*)(o + (size_t)r * WCONST))[0] = acc[r];
}

// ---------------------------------------------------------------------------
extern "C" void kernel_launch(void* const* d_in, const int* in_sizes, int n_in,
                              void* d_out, int out_size, void* d_ws, size_t ws_size,
                              hipStream_t stream) {
    const float* pred       = (const float*)d_in[0];
    const float* nodes      = (const float*)d_in[1];
    const int*   batch_list = (const int*)d_in[2];

    const int N = in_sizes[0];                    // 1024
    const int B = out_size / (HCONST * WCONST);   // 64

    float* out = (float*)d_out;

    fused_kernel<<<B * TILES, 256, 0, stream>>>(pred, nodes, batch_list, N, out);
}